// Round 17
// baseline (648.411 us; speedup 1.0000x reference)
//
#include <hip/hip_runtime.h>
#include <math.h>

#define DIMC 384
#define NHEADS 8
#define CHD 48
#define HWN 16384
#define IMW 128
#define PERT ((size_t)DIMC * HWN)   // elements per [384,128,128] tensor
#define WELEM (DIMC * DIMC)         // 147456
#define NB 8

typedef short short8 __attribute__((ext_vector_type(8)));
typedef unsigned short u16x8 __attribute__((ext_vector_type(8)));
typedef float f32x4 __attribute__((ext_vector_type(4)));

__device__ __forceinline__ unsigned short f2bf(float f) {
  unsigned int u = __float_as_uint(f);
  unsigned int r = (u + 0x7fffu + ((u >> 16) & 1u)) >> 16;   // RNE
  return (unsigned short)r;
}
__device__ __forceinline__ float bf2f(unsigned short b) {
  return __uint_as_float(((unsigned int)b) << 16);
}
__device__ __forceinline__ void async16(const void* g, void* l) {
  __builtin_amdgcn_global_load_lds(
      (const __attribute__((address_space(1))) void*)g,
      (__attribute__((address_space(3))) void*)l, 16, 0, 0);
}

#define WAITVM(n) asm volatile("s_waitcnt vmcnt(" #n ")" ::: "memory")
#define SBAR()                                 \
  do {                                         \
    __builtin_amdgcn_sched_barrier(0);         \
    __builtin_amdgcn_s_barrier();              \
    __builtin_amdgcn_sched_barrier(0);         \
  } while (0)

// ---------------------------------------------------------------------------
// PERSISTENT-A streaming conv GEMM (short-K fix): each block loads its
// 128x384 A-panel into LDS ONCE (96 KB), then streams 4 n-tiles through a
// B-only double buffer (2x16 KB). 24 contiguous K-steps per block — the
// pipeline never drains across n-tiles; A restaging eliminated.
// 256 thr, 4 waves 2Mx2N (64x64/wave, acc[4][4], 32 MFMA/wave/step).
// vmcnt ledger: prologue A(24)+B0(4); step s stages B(s+1) [4 loads],
// WAITVM(4) retires B(s). buf = t&1 (6 steps/n-tile, even). WAR: top SBAR.
// C-write per n-tile: scalar stores (R10: no LDS bounce); their vmcnt drain
// at the next boundary wait is accepted (~1/6 steps).
// Grid 2304 = 8b x 32nc x (3j x 3mt) = exactly 9 CU-rounds; XCD-swizzled so
// the 9 blocks sharing one B-panel are adjacent.
// A (Wc) and BT (XT) pre-XOR-swizzled per 128B k-chunk:
//   element (r,k) at (k&~63) | ((k&63) ^ ((r&7)<<3)); ds_read applies XOR.
// ---------------------------------------------------------------------------
__global__ __launch_bounds__(256) void k_conv_mfma(
    const unsigned short* __restrict__ Wc, const unsigned short* __restrict__ XT,
    unsigned short* __restrict__ Y)
{
  __shared__ unsigned short Ap[6][8192];   // 96 KB: [k-chunk][128 rows x 128B]
  __shared__ unsigned short Bs[2][8192];   // 2 x 16 KB

  int lin = (int)blockIdx.x;               // 0..2303
  int swz = (lin & 7) * 288 + (lin >> 3);  // 2304/8 per XCD
  int g = swz / 9, r = swz - g * 9;        // g = b*32+nc ; r = j*3+mt
  int b = g >> 5, nc = g & 31;
  int j = r / 3, mt = r - j * 3;

  const unsigned short* A = Wc + j * WELEM + (size_t)(mt * 128) * DIMC;
  const unsigned short* XTb = XT + (size_t)b * PERT;
  unsigned short* Yb = Y + (size_t)b * 3 * PERT + (size_t)j * PERT;
  const int nbase0 = nc * 512;

  const int tid = threadIdx.x;
  const int lane = tid & 63;
  const int wv = tid >> 6;              // 0..3
  const int wm = (wv >> 1) * 64;
  const int wn = (wv & 1) * 64;

  const unsigned short* asrc = A + (size_t)(tid >> 3) * DIMC + (tid & 7) * 8;
  const unsigned short* bsrc =
      XTb + (size_t)(nbase0 + (tid >> 3)) * DIMC + (tid & 7) * 8;

  const int ar = wm + (lane & 15);
  const int br = wn + (lane & 15);
  const int kg = (lane >> 4) << 4;      // byte offset base within 128B chunk
  const int sw = (lane & 7) << 4;       // row-XOR swizzle

  f32x4 acc[4][4];
#pragma unroll
  for (int i = 0; i < 4; ++i)
#pragma unroll
    for (int jj = 0; jj < 4; ++jj) acc[i][jj] = (f32x4){0.f, 0.f, 0.f, 0.f};

#define STAGE_B(buf, nt, t)                                              \
  do {                                                                   \
    _Pragma("unroll") for (int i = 0; i < 4; ++i)                        \
        async16(bsrc + (size_t)((nt) * 128 + i * 32) * DIMC + (t) * 64,  \
                &Bs[buf][(size_t)(tid + i * 256) * 8]);                  \
  } while (0)

#define COMPUTE(kc, buf)                                                 \
  do {                                                                   \
    short8 af[2][4], bf[2][4];                                           \
    _Pragma("unroll") for (int kq = 0; kq < 2; ++kq) {                   \
      const int kb = kq * 64 + kg;                                       \
      _Pragma("unroll") for (int mi = 0; mi < 4; ++mi)                   \
          af[kq][mi] = *reinterpret_cast<const short8*>(                 \
              (const char*)&Ap[kc][0] + (ar + mi * 16) * 128 + (kb ^ sw)); \
      _Pragma("unroll") for (int ni = 0; ni < 4; ++ni)                   \
          bf[kq][ni] = *reinterpret_cast<const short8*>(                 \
              (const char*)&Bs[buf][0] + (br + ni * 16) * 128 + (kb ^ sw)); \
    }                                                                    \
    __builtin_amdgcn_s_setprio(1);                                       \
    _Pragma("unroll") for (int kq = 0; kq < 2; ++kq)                     \
      _Pragma("unroll") for (int mi = 0; mi < 4; ++mi)                   \
        _Pragma("unroll") for (int ni = 0; ni < 4; ++ni)                 \
          acc[mi][ni] = __builtin_amdgcn_mfma_f32_16x16x32_bf16(         \
              af[kq][mi], bf[kq][ni], acc[mi][ni], 0, 0, 0);             \
    __builtin_amdgcn_s_setprio(0);                                       \
  } while (0)

  // prologue: A (24 loads) + B(nt=0,t=0) into buf0
#pragma unroll
  for (int kc = 0; kc < 6; ++kc)
#pragma unroll
    for (int i = 0; i < 4; ++i)
      async16(asrc + (size_t)(i * 32) * DIMC + kc * 64,
              &Ap[kc][(size_t)(tid + i * 256) * 8]);
  STAGE_B(0, 0, 0);

  for (int nt = 0; nt < 4; ++nt) {
#pragma unroll
    for (int t = 0; t < 6; ++t) {
      const int buf = t & 1;
      SBAR();                                   // WAR: buf^1's last reader done
      if (t < 5) {
        STAGE_B(buf ^ 1, nt, t + 1);
        WAITVM(4); SBAR();
      } else if (nt < 3) {
        STAGE_B(0, nt + 1, 0);                  // (s+1)&1 == 0 here
        WAITVM(4); SBAR();
      } else {
        WAITVM(0); SBAR();                      // final step: drain
      }
      COMPUTE(t, buf);
    }
    // C-write for this n-tile, then reset acc
    {
      const int orow = mt * 128 + wm + ((lane >> 4) << 2);
      const int ocol = nbase0 + nt * 128 + wn + (lane & 15);
#pragma unroll
      for (int mi = 0; mi < 4; ++mi)
#pragma unroll
        for (int ni = 0; ni < 4; ++ni)
#pragma unroll
          for (int rr = 0; rr < 4; ++rr)
            Yb[(size_t)(orow + mi * 16 + rr) * HWN + ocol + ni * 16] =
                f2bf(acc[mi][ni][rr]);
#pragma unroll
      for (int i = 0; i < 4; ++i)
#pragma unroll
        for (int jj = 0; jj < 4; ++jj) acc[i][jj] = (f32x4){0.f, 0.f, 0.f, 0.f};
    }
  }
#undef STAGE_B
#undef COMPUTE
}

// ---------------------------------------------------------------------------
// R14/R15-proven FULL-M GEMM body (for the final matmul; conv 180us config).
// BM=384 x BN=128, BK=64, 512 thr (8 waves 4Mx2N, 96x64/wave, acc[6][4]).
// ---------------------------------------------------------------------------
template <int OUTBF>
__device__ __forceinline__ void gemm384_body(
    const unsigned short* __restrict__ A,
    const unsigned short* __restrict__ BT,
    void* __restrict__ Y, int nbase)
{
  __shared__ unsigned short As[2][24576];   // 2 x 48 KB (384 rows x 128B)
  __shared__ unsigned short Bs[2][8192];    // 2 x 16 KB (128 rows x 128B)
  const int tid = threadIdx.x;
  const int lane = tid & 63;
  const int wv = tid >> 6;              // 0..7
  const int wm = (wv >> 1) * 96;
  const int wn = (wv & 1) * 64;

  f32x4 acc[6][4];
#pragma unroll
  for (int i = 0; i < 6; ++i)
#pragma unroll
    for (int j = 0; j < 4; ++j) acc[i][j] = (f32x4){0.f, 0.f, 0.f, 0.f};

  const unsigned short* asrc = A + (size_t)(tid >> 3) * DIMC + (tid & 7) * 8;
  const unsigned short* bsrc =
      BT + (size_t)(nbase + (tid >> 3)) * DIMC + (tid & 7) * 8;

  const int ar = wm + (lane & 15);
  const int br = wn + (lane & 15);
  const int kg = (lane >> 4) << 4;
  const int sw = (lane & 7) << 4;

#define STAGE(buf, k0)                                                   \
  do {                                                                   \
    _Pragma("unroll") for (int i = 0; i < 6; ++i)                        \
        async16(asrc + (size_t)(i * 64) * DIMC + (k0),                   \
                &As[buf][(size_t)(tid + i * 512) * 8]);                  \
    _Pragma("unroll") for (int i = 0; i < 2; ++i)                        \
        async16(bsrc + (size_t)(i * 64) * DIMC + (k0),                   \
                &Bs[buf][(size_t)(tid + i * 512) * 8]);                  \
  } while (0)

#define COMPUTE(buf)                                                     \
  do {                                                                   \
    short8 af[2][6], bf[2][4];                                           \
    _Pragma("unroll") for (int kq = 0; kq < 2; ++kq) {                   \
      const int kb = kq * 64 + kg;                                       \
      _Pragma("unroll") for (int mi = 0; mi < 6; ++mi)                   \
          af[kq][mi] = *reinterpret_cast<const short8*>(                 \
              (const char*)&As[buf][0] + (ar + mi * 16) * 128 + (kb ^ sw)); \
      _Pragma("unroll") for (int ni = 0; ni < 4; ++ni)                   \
          bf[kq][ni] = *reinterpret_cast<const short8*>(                 \
              (const char*)&Bs[buf][0] + (br + ni * 16) * 128 + (kb ^ sw)); \
    }                                                                    \
    __builtin_amdgcn_s_setprio(1);                                       \
    _Pragma("unroll") for (int kq = 0; kq < 2; ++kq)                     \
      _Pragma("unroll") for (int mi = 0; mi < 6; ++mi)                   \
        _Pragma("unroll") for (int ni = 0; ni < 4; ++ni)                 \
          acc[mi][ni] = __builtin_amdgcn_mfma_f32_16x16x32_bf16(         \
              af[kq][mi], bf[kq][ni], acc[mi][ni], 0, 0, 0);             \
    __builtin_amdgcn_s_setprio(0);                                       \
  } while (0)

  STAGE(0, 0);
  WAITVM(0); SBAR();
  STAGE(1, 64);            COMPUTE(0);
  SBAR(); STAGE(0, 128); WAITVM(8); SBAR(); COMPUTE(1);
  SBAR(); STAGE(1, 192); WAITVM(8); SBAR(); COMPUTE(0);
  SBAR(); STAGE(0, 256); WAITVM(8); SBAR(); COMPUTE(1);
  SBAR(); STAGE(1, 320); WAITVM(8); SBAR(); COMPUTE(0);
  WAITVM(0); SBAR(); COMPUTE(1);

#undef STAGE
#undef COMPUTE

  const int orow = wm + ((lane >> 4) << 2);
  const int ocol = nbase + wn + (lane & 15);
#pragma unroll
  for (int mi = 0; mi < 6; ++mi)
#pragma unroll
    for (int ni = 0; ni < 4; ++ni)
#pragma unroll
      for (int r = 0; r < 4; ++r) {
        size_t off = (size_t)(orow + mi * 16 + r) * HWN + ocol + ni * 16;
        if (OUTBF) ((unsigned short*)Y)[off] = f2bf(acc[mi][ni][r]);
        else       ((float*)Y)[off] = acc[mi][ni][r];
      }
}

// out[b] = M[b] @ v[b] (full M=384). grid (128, 8), 512 thr.
__global__ __launch_bounds__(512) void k_final_mfma(
    const unsigned short* __restrict__ M, const unsigned short* __restrict__ vT,
    float* __restrict__ out)
{
  int lin = (int)blockIdx.y * 128 + blockIdx.x;      // 0..1023
  int swz = (lin & 7) * 128 + (lin >> 3);
  int bb = swz >> 7, nt = swz & 127;
  gemm384_body<0>(M + (size_t)bb * WELEM, vT + (size_t)bb * PERT,
                  out + (size_t)bb * PERT, nt * 128);
}

// transpose+convert x[b][c][n] f32 -> XT[b][n][c] bf16, rows XOR-swizzled.
__global__ __launch_bounds__(256) void k_transpose_x(
    const float* __restrict__ x, unsigned short* __restrict__ XT)
{
  __shared__ unsigned short S[64][72];
  int n0 = blockIdx.x * 64, c0 = blockIdx.y * 64;
  const float* xb = x + (size_t)blockIdx.z * PERT;
  unsigned short* XTb = XT + (size_t)blockIdx.z * PERT;
  int t = threadIdx.x;
  int cl = t >> 2, ns = (t & 3) * 16;
  const float* src = &xb[(size_t)(c0 + cl) * HWN + n0 + ns];
#pragma unroll
  for (int i = 0; i < 16; i += 4) {
    float4 v = *reinterpret_cast<const float4*>(&src[i]);
    S[cl][ns + i + 0] = f2bf(v.x);
    S[cl][ns + i + 1] = f2bf(v.y);
    S[cl][ns + i + 2] = f2bf(v.z);
    S[cl][ns + i + 3] = f2bf(v.w);
  }
  __syncthreads();
  int nl = t >> 2, cs = (t & 3) * 16;
  unsigned short tmp[16];
#pragma unroll
  for (int i = 0; i < 16; ++i) tmp[i] = S[cs + i][nl];
  u16x8 p0, p1;
#pragma unroll
  for (int i = 0; i < 8; ++i) { p0[i] = tmp[i]; p1[i] = tmp[8 + i]; }
  char* rowb = (char*)XTb + (size_t)(n0 + nl) * (DIMC * 2);
  int cb = (c0 + cs) * 2;
  int sw = (nl & 7) << 4;
  *reinterpret_cast<u16x8*>(rowb + ((cb) ^ sw)) = p0;
  *reinterpret_cast<u16x8*>(rowb + ((cb + 16) ^ sw)) = p1;
}

// w -> bf16, stored XOR-swizzled per 64-elem k-chunk (A-operand layout).
__global__ __launch_bounds__(256) void k_convert_w(
    const float* __restrict__ w0, const float* __restrict__ w1,
    const float* __restrict__ w2, unsigned short* __restrict__ Wc)
{
  int idx = blockIdx.x * 256 + threadIdx.x;      // < 3*147456
  int j = idx / WELEM, r = idx - j * WELEM;
  int m = r / DIMC, k = r - m * DIMC;
  const float* s = (j == 0) ? w0 : (j == 1) ? w1 : w2;
  int kd = (k & ~63) | ((k & 63) ^ ((m & 7) << 3));
  Wc[j * WELEM + m * DIMC + kd] = f2bf(s[r]);
}

// depthwise 3x3 SAME for q,k planes only (j<2), bf16 in/out, 16 px/thread;
// halo via __shfl. 4 blocks per plane; per-block sum-of-squares partial.
__global__ __launch_bounds__(256) void k_dwconv(
    const unsigned short* __restrict__ Yin, const float* __restrict__ dw0,
    const float* __restrict__ dw1,
    unsigned short* __restrict__ Zout, float* __restrict__ partial)
{
  __shared__ float red[4];
  int gid = blockIdx.x * 256 + threadIdx.x;    // unit = 16 px
  int plane = gid >> 10;                        // 1024 units per plane
  int rem = gid & 1023;
  int b = plane / 768;
  int pl = plane - b * 768;                     // j*384 + c
  int j = pl / DIMC;
  int c = pl - j * DIMC;
  int h = rem >> 3;
  int wg = (rem & 7) << 4;                      // 0,16,...,112
  int lane = threadIdx.x & 63;                  // lane&7 == rem&7
  const float* dw = ((j == 0) ? dw0 : dw1) + c * 9;
  const unsigned short* src = Yin + ((size_t)(b * 3 + j) * DIMC + c) * HWN;

  float acc[16];
#pragma unroll
  for (int i = 0; i < 16; ++i) acc[i] = 0.f;

#pragma unroll
  for (int dy = -1; dy <= 1; ++dy) {
    int hh = h + dy;
    bool valid = (hh >= 0) && (hh < IMW);
    float mf[16];
    if (valid) {
      const unsigned short* row = src + hh * IMW + wg;
      u16x8 a0 = *reinterpret_cast<const u16x8*>(row);
      u16x8 a1 = *reinterpret_cast<const u16x8*>(row + 8);
#pragma unroll
      for (int i = 0; i < 8; ++i) { mf[i] = bf2f(a0[i]); mf[8 + i] = bf2f(a1[i]); }
    } else {
#pragma unroll
      for (int i = 0; i < 16; ++i) mf[i] = 0.f;
    }
    float lf = __shfl_up(mf[15], 1);
    float rf = __shfl_down(mf[0], 1);
    if ((lane & 7) == 0) lf = 0.f;
    if ((lane & 7) == 7) rf = 0.f;
    float t0 = dw[(dy + 1) * 3], t1 = dw[(dy + 1) * 3 + 1], t2 = dw[(dy + 1) * 3 + 2];
    acc[0] = fmaf(lf, t0, fmaf(mf[0], t1, fmaf(mf[1], t2, acc[0])));
#pragma unroll
    for (int i = 1; i < 15; ++i)
      acc[i] = fmaf(mf[i - 1], t0, fmaf(mf[i], t1, fmaf(mf[i + 1], t2, acc[i])));
    acc[15] = fmaf(mf[14], t0, fmaf(mf[15], t1, fmaf(rf, t2, acc[15])));
  }

  u16x8 o0, o1;
#pragma unroll
  for (int i = 0; i < 8; ++i) { o0[i] = f2bf(acc[i]); o1[i] = f2bf(acc[8 + i]); }
  unsigned short* dst =
      Zout + ((size_t)(b * 3 + j) * DIMC + c) * HWN + h * IMW + wg;
  *reinterpret_cast<u16x8*>(dst) = o0;
  *reinterpret_cast<u16x8*>(dst + 8) = o1;

  float s = 0.f;
#pragma unroll
  for (int i = 0; i < 16; ++i) s = fmaf(acc[i], acc[i], s);
#pragma unroll
  for (int off = 32; off > 0; off >>= 1) s += __shfl_down(s, off);
  if ((threadIdx.x & 63) == 0) red[threadIdx.x >> 6] = s;
  __syncthreads();
  if (threadIdx.x == 0)
    partial[blockIdx.x] = red[0] + red[1] + red[2] + red[3];
}

// depthwise 3x3 for v planes, FUSED with transpose: writes ONLY vT[b][n][c]
// bf16 (rows XOR-swizzled, B-operand layout). grid (128 h, 12 cgrp, 8 b).
__global__ __launch_bounds__(256) void k_dwconv_v(
    const unsigned short* __restrict__ Yin, const float* __restrict__ dw2,
    unsigned short* __restrict__ vT)
{
  __shared__ unsigned short S[128][40];   // [px][c_l]
  int h = blockIdx.x;
  int cgrp = blockIdx.y;
  int b = blockIdx.z;
  int t = threadIdx.x;
  int c_l = t >> 3;            // 0..31
  int seg = t & 7;
  int wg = seg << 4;
  int lane = t & 63;           // lane&7 == seg
  int c = cgrp * 32 + c_l;
  const float* dw = dw2 + c * 9;
  const unsigned short* src = Yin + ((size_t)(b * 3 + 2) * DIMC + c) * HWN;

  float acc[16];
#pragma unroll
  for (int i = 0; i < 16; ++i) acc[i] = 0.f;

#pragma unroll
  for (int dy = -1; dy <= 1; ++dy) {
    int hh = h + dy;
    bool valid = (hh >= 0) && (hh < IMW);
    float mf[16];
    if (valid) {
      const unsigned short* row = src + hh * IMW + wg;
      u16x8 a0 = *reinterpret_cast<const u16x8*>(row);
      u16x8 a1 = *reinterpret_cast<const u16x8*>(row + 8);
#pragma unroll
      for (int i = 0; i < 8; ++i) { mf[i] = bf2f(a0[i]); mf[8 + i] = bf2f(a1[i]); }
    } else {
#pragma unroll
      for (int i = 0; i < 16; ++i) mf[i] = 0.f;
    }
    float lf = __shfl_up(mf[15], 1);
    float rf = __shfl_down(mf[0], 1);
    if ((lane & 7) == 0) lf = 0.f;
    if ((lane & 7) == 7) rf = 0.f;
    float t0 = dw[(dy + 1) * 3], t1 = dw[(dy + 1) * 3 + 1], t2 = dw[(dy + 1) * 3 + 2];
    acc[0] = fmaf(lf, t0, fmaf(mf[0], t1, fmaf(mf[1], t2, acc[0])));
#pragma unroll
    for (int i = 1; i < 15; ++i)
      acc[i] = fmaf(mf[i - 1], t0, fmaf(mf[i], t1, fmaf(mf[i + 1], t2, acc[i])));
    acc[15] = fmaf(mf[14], t0, fmaf(mf[15], t1, fmaf(rf, t2, acc[15])));
  }

#pragma unroll
  for (int i = 0; i < 16; ++i) S[wg + i][c_l] = f2bf(acc[i]);
  __syncthreads();

  int px = t >> 1, half = t & 1;
  int n = h * IMW + px;
  u16x8 p0 = *reinterpret_cast<const u16x8*>(&S[px][half * 16]);
  u16x8 p1 = *reinterpret_cast<const u16x8*>(&S[px][half * 16 + 8]);
  char* rowb = (char*)(vT + (size_t)b * PERT) + (size_t)n * (DIMC * 2);
  int cb = (cgrp * 32 + half * 16) * 2;
  int sw = (n & 7) << 4;
  int chunk = cb & ~127, off = cb & 127;
  *reinterpret_cast<u16x8*>(rowb + chunk + ((off) ^ sw)) = p0;
  *reinterpret_cast<u16x8*>(rowb + chunk + ((off + 16) ^ sw)) = p1;
}

// q@k^T partials: grid 512 = (b, h, slice of 2048 px). 4 waves x 512 px.
__global__ __launch_bounds__(256) void k_qk_mfma(
    const unsigned short* __restrict__ qkv, float* __restrict__ Spart)
{
  __shared__ float Sred[4][2304];
  int blk = blockIdx.x;
  int b = blk >> 6, h = (blk >> 3) & 7, slice = blk & 7;
  int tid = threadIdx.x, lane = tid & 63, w = tid >> 6;
  const unsigned short* qb = qkv + ((size_t)b * 3 * DIMC + h * CHD) * HWN;
  const unsigned short* kb = qb + (size_t)DIMC * HWN;
  const int row = lane & 15;
  const int ko = (lane >> 4) << 3;
  const int n0 = slice * 2048 + w * 512;

  f32x4 acc[3][3];
#pragma unroll
  for (int i = 0; i < 3; ++i)
#pragma unroll
    for (int j = 0; j < 3; ++j) acc[i][j] = (f32x4){0.f, 0.f, 0.f, 0.f};

  for (int ns = n0; ns < n0 + 512; ns += 32) {
    short8 aq[3], bk[3];
#pragma unroll
    for (int mi = 0; mi < 3; ++mi)
      aq[mi] = *reinterpret_cast<const short8*>(&qb[(size_t)(mi * 16 + row) * HWN + ns + ko]);
#pragma unroll
    for (int ni = 0; ni < 3; ++ni)
      bk[ni] = *reinterpret_cast<const short8*>(&kb[(size_t)(ni * 16 + row) * HWN + ns + ko]);
#pragma unroll
    for (int mi = 0; mi < 3; ++mi)
#pragma unroll
      for (int ni = 0; ni < 3; ++ni)
        acc[mi][ni] = __builtin_amdgcn_mfma_f32_16x16x32_bf16(
            aq[mi], bk[ni], acc[mi][ni], 0, 0, 0);
  }
  const int c0 = (lane >> 4) << 2;
#pragma unroll
  for (int mi = 0; mi < 3; ++mi)
#pragma unroll
    for (int ni = 0; ni < 3; ++ni)
#pragma unroll
      for (int r = 0; r < 4; ++r)
        Sred[w][(mi * 16 + c0 + r) * 48 + ni * 16 + row] = acc[mi][ni][r];
  __syncthreads();
  float* dst = Spart + (size_t)blk * 2304;
#pragma unroll
  for (int i = 0; i < 9; ++i) {
    int e = tid + i * 256;
    dst[e] = Sred[0][e] + Sred[1][e] + Sred[2][e] + Sred[3][e];
  }
}

// slice-sum + L2-norm scale + softmax. grid = 8 (per b), 384 thr = row (h,c).
__global__ __launch_bounds__(384) void k_attn_sm(
    const float* __restrict__ Spart, const float* __restrict__ partial,
    const float* __restrict__ temp, float* __restrict__ Aat)
{
  __shared__ float sk[DIMC];
  int b = blockIdx.x, t = threadIdx.x;
  int h = t / CHD, c = t - h * CHD;
  float sq = 0.f, skk = 0.f;
#pragma unroll
  for (int s = 0; s < 4; ++s) {
    sq  += partial[((size_t)b * 768 + t) * 4 + s];
    skk += partial[((size_t)b * 768 + DIMC + t) * 4 + s];
  }
  sk[t] = 1.f / fmaxf(sqrtf(skk), 1e-12f);
  float invq = 1.f / fmaxf(sqrtf(sq), 1e-12f);
  __syncthreads();
  float vals[CHD];
#pragma unroll
  for (int d = 0; d < CHD; ++d) vals[d] = 0.f;
  for (int sl = 0; sl < 8; ++sl) {
    const float* sp = Spart + (size_t)(b * 64 + h * 8 + sl) * 2304 + c * 48;
#pragma unroll
    for (int d = 0; d < CHD; ++d) vals[d] += sp[d];
  }
  float tp = temp[h];
  float vq = invq * tp;
  float mx = -1e30f;
#pragma unroll
  for (int d = 0; d < CHD; ++d) {
    vals[d] *= vq * sk[h * CHD + d];
    mx = fmaxf(mx, vals[d]);
  }
  float sum = 0.f;
#pragma unroll
  for (int d = 0; d < CHD; ++d) { vals[d] = expf(vals[d] - mx); sum += vals[d]; }
  float inv = 1.f / sum;
  float* Arow = Aat + ((size_t)(b * 8 + h) * 48 + c) * 48;
#pragma unroll
  for (int d = 0; d < CHD; ++d) Arow[d] = vals[d] * inv;
}

// M[b][o][h*48+d] = sum_c wproj[o][h*48+c] * A[b][h*48+c][d], bf16 out,
// stored XOR-swizzled (A-operand layout for k_final_mfma).
__global__ __launch_bounds__(256) void k_combine(
    const float* __restrict__ wproj, const float* __restrict__ Aat,
    unsigned short* __restrict__ M)
{
  int idx = blockIdx.x * 256 + threadIdx.x;      // over 8*384*384
  int b = idx / WELEM;
  int r2 = idx - b * WELEM;
  int o = r2 / DIMC;
  int dg = r2 - o * DIMC;
  int h = dg / CHD, d = dg - h * CHD;
  const float* wrow = wproj + (size_t)o * DIMC + h * CHD;
  const float* Acol = Aat + (size_t)b * DIMC * CHD + (size_t)(h * CHD) * CHD + d;
  float s = 0.f;
#pragma unroll
  for (int c = 0; c < CHD; ++c)
    s = fmaf(wrow[c], Acol[c * CHD], s);
  int dd = (dg & ~63) | ((dg & 63) ^ ((o & 7) << 3));
  M[b * WELEM + o * DIMC + dd] = f2bf(s);
}

extern "C" void kernel_launch(void* const* d_in, const int* in_sizes, int n_in,
                              void* d_out, int out_size, void* d_ws, size_t ws_size,
                              hipStream_t stream)
{
  const float* x     = (const float*)d_in[0];
  const float* w0    = (const float*)d_in[1];
  const float* w1    = (const float*)d_in[2];
  const float* w2    = (const float*)d_in[3];
  const float* dw0   = (const float*)d_in[4];
  const float* dw1   = (const float*)d_in[5];
  const float* dw2   = (const float*)d_in[6];
  const float* wproj = (const float*)d_in[7];
  const float* temp  = (const float*)d_in[8];
  float* out = (float*)d_out;

  // ws layout. vT aliases XT (XT dead after conv_mfma; dwconv_v runs after).
  char* p = (char*)d_ws;
  unsigned short* Wc     = (unsigned short*)p;  p += (size_t)3 * WELEM * 2;            // 884,736
  unsigned short* XT     = (unsigned short*)p;  p += (size_t)NB * PERT * 2;            // 100.7 MB
  unsigned short* q0k0v0 = (unsigned short*)p;  p += (size_t)NB * 3 * PERT * 2;        // 302 MB
  unsigned short* qkv    = (unsigned short*)p;  p += (size_t)NB * 3 * PERT * 2;        // 302 MB (v third unused)
  float* Spart   = (float*)p;  p += (size_t)512 * 2304 * 4;                            // 4.7 MB
  float* Aat     = (float*)p;  p += (size_t)NB * DIMC * CHD * 4;                       // 590 KB
  float* partial = (float*)p;  p += (size_t)NB * 2 * DIMC * 4 * 4;                     // 98 KB
  unsigned short* Mbf = (unsigned short*)p;                                            // 2.36 MB
  unsigned short* vT = XT;   // alias

  k_convert_w<<<(3 * WELEM + 255) / 256, 256, 0, stream>>>(w0, w1, w2, Wc);
  k_transpose_x<<<dim3(256, 6, NB), 256, 0, stream>>>(x, XT);
  k_conv_mfma<<<2304, 256, 0, stream>>>(Wc, XT, q0k0v0);
  k_dwconv<<<NB * 2 * DIMC * 4, 256, 0, stream>>>(q0k0v0, dw0, dw1, qkv, partial);
  k_dwconv_v<<<dim3(128, 12, NB), 256, 0, stream>>>(q0k0v0, dw2, vT);
  k_qk_mfma<<<512, 256, 0, stream>>>(qkv, Spart);
  k_attn_sm<<<NB, 384, 0, stream>>>(Spart, partial, temp, Aat);
  k_combine<<<(NB * WELEM) / 256, 256, 0, stream>>>(wproj, Aat, Mbf);
  k_final_mfma<<<dim3(128, NB), 512, 0, stream>>>(Mbf, vT, out);
  (void)in_sizes; (void)n_in; (void)out_size; (void)ws_size;
}

// Round 18
// 557.802 us; speedup vs baseline: 1.1624x; 1.1624x over previous
//
#include <hip/hip_runtime.h>
#include <math.h>

#define DIMC 384
#define NHEADS 8
#define CHD 48
#define HWN 16384
#define IMW 128
#define PERT ((size_t)DIMC * HWN)   // elements per [384,128,128] tensor
#define WELEM (DIMC * DIMC)         // 147456
#define NB 8

typedef short short8 __attribute__((ext_vector_type(8)));
typedef unsigned short u16x8 __attribute__((ext_vector_type(8)));
typedef float f32x4 __attribute__((ext_vector_type(4)));

__device__ __forceinline__ unsigned short f2bf(float f) {
  unsigned int u = __float_as_uint(f);
  unsigned int r = (u + 0x7fffu + ((u >> 16) & 1u)) >> 16;   // RNE
  return (unsigned short)r;
}
__device__ __forceinline__ float bf2f(unsigned short b) {
  return __uint_as_float(((unsigned int)b) << 16);
}
__device__ __forceinline__ void async16(const void* g, void* l) {
  __builtin_amdgcn_global_load_lds(
      (const __attribute__((address_space(1))) void*)g,
      (__attribute__((address_space(3))) void*)l, 16, 0, 0);
}

// ---------------------------------------------------------------------------
// bf16 MFMA GEMM, FULL-M tile (BEST MEASURED: conv 179us, MfmaUtil 27%,
// total 558us — R15 config restored after persistent-A (249us) and
// 2-blk/CU (188us) both regressed).
// BM=384 x BN=128, BK=64, 512 thr (8 waves 4Mx2N, 96x64/wave, acc[6][4]).
// LDS: A dbuf 2x48KB + B dbuf 2x16KB = 128 KB. Compute chain buf 0,1,0,1,0,1.
// Schedule per K-step t>=1:  SBAR; STAGE(buf(t+1)); WAITVM(8); SBAR;
// COMPUTE(buf(t)).
// A-path via global_load_lds staging (R12: per-lane direct A-loads regressed).
// Scalar epilogue (R10: LDS-bounce = 1.8x HBM write amplification).
// A and BT global storage pre-XOR-swizzled per 128B k-chunk:
//   element (r,k) at (k&~63) | ((k&63) ^ ((r&7)<<3)); ds_read applies XOR.
// ---------------------------------------------------------------------------
template <int OUTBF>
__device__ __forceinline__ void gemm384_body(
    const unsigned short* __restrict__ A,
    const unsigned short* __restrict__ BT,
    void* __restrict__ Y, int nbase)
{
  __shared__ unsigned short As[2][24576];   // 2 x 48 KB (384 rows x 128B)
  __shared__ unsigned short Bs[2][8192];    // 2 x 16 KB (128 rows x 128B)
  const int tid = threadIdx.x;
  const int lane = tid & 63;
  const int wv = tid >> 6;              // 0..7
  const int wm = (wv >> 1) * 96;        // 4 M-quads of 96 rows
  const int wn = (wv & 1) * 64;         // 2 N-halves of 64 cols

  f32x4 acc[6][4];
#pragma unroll
  for (int i = 0; i < 6; ++i)
#pragma unroll
    for (int j = 0; j < 4; ++j) acc[i][j] = (f32x4){0.f, 0.f, 0.f, 0.f};

  const unsigned short* asrc = A + (size_t)(tid >> 3) * DIMC + (tid & 7) * 8;
  const unsigned short* bsrc =
      BT + (size_t)(nbase + (tid >> 3)) * DIMC + (tid & 7) * 8;

  const int ar = wm + (lane & 15);
  const int br = wn + (lane & 15);
  const int kg = (lane >> 4) << 4;      // byte offset base within 128B chunk
  const int sw = (lane & 7) << 4;       // row-XOR swizzle

#define WAITVM(n) asm volatile("s_waitcnt vmcnt(" #n ")" ::: "memory")
#define SBAR()                                 \
  do {                                         \
    __builtin_amdgcn_sched_barrier(0);         \
    __builtin_amdgcn_s_barrier();              \
    __builtin_amdgcn_sched_barrier(0);         \
  } while (0)

#define STAGE(buf, k0)                                                   \
  do {                                                                   \
    _Pragma("unroll") for (int i = 0; i < 6; ++i)                        \
        async16(asrc + (size_t)(i * 64) * DIMC + (k0),                   \
                &As[buf][(size_t)(tid + i * 512) * 8]);                  \
    _Pragma("unroll") for (int i = 0; i < 2; ++i)                        \
        async16(bsrc + (size_t)(i * 64) * DIMC + (k0),                   \
                &Bs[buf][(size_t)(tid + i * 512) * 8]);                  \
  } while (0)

#define COMPUTE(buf)                                                     \
  do {                                                                   \
    short8 af[2][6], bf[2][4];                                           \
    _Pragma("unroll") for (int kq = 0; kq < 2; ++kq) {                   \
      const int kb = kq * 64 + kg;                                       \
      _Pragma("unroll") for (int mi = 0; mi < 6; ++mi)                   \
          af[kq][mi] = *reinterpret_cast<const short8*>(                 \
              (const char*)&As[buf][0] + (ar + mi * 16) * 128 + (kb ^ sw)); \
      _Pragma("unroll") for (int ni = 0; ni < 4; ++ni)                   \
          bf[kq][ni] = *reinterpret_cast<const short8*>(                 \
              (const char*)&Bs[buf][0] + (br + ni * 16) * 128 + (kb ^ sw)); \
    }                                                                    \
    __builtin_amdgcn_s_setprio(1);                                       \
    _Pragma("unroll") for (int kq = 0; kq < 2; ++kq)                     \
      _Pragma("unroll") for (int mi = 0; mi < 6; ++mi)                   \
        _Pragma("unroll") for (int ni = 0; ni < 4; ++ni)                 \
          acc[mi][ni] = __builtin_amdgcn_mfma_f32_16x16x32_bf16(         \
              af[kq][mi], bf[kq][ni], acc[mi][ni], 0, 0, 0);             \
    __builtin_amdgcn_s_setprio(0);                                       \
  } while (0)

  // K-tiles t=0..5 live in buf t&1.
  STAGE(0, 0);
  WAITVM(0); SBAR();                         // buf0 (t0) ready for all waves
  STAGE(1, 64);            COMPUTE(0);       // stage t1 flies over compute t0
  SBAR(); STAGE(0, 128); WAITVM(8); SBAR(); COMPUTE(1);   // t1 (buf1)
  SBAR(); STAGE(1, 192); WAITVM(8); SBAR(); COMPUTE(0);   // t2 (buf0)
  SBAR(); STAGE(0, 256); WAITVM(8); SBAR(); COMPUTE(1);   // t3 (buf1)
  SBAR(); STAGE(1, 320); WAITVM(8); SBAR(); COMPUTE(0);   // t4 (buf0)
  WAITVM(0); SBAR(); COMPUTE(1);                          // t5 (buf1)

#undef STAGE
#undef COMPUTE
#undef WAITVM
#undef SBAR

  const int orow = wm + ((lane >> 4) << 2);
  const int ocol = nbase + wn + (lane & 15);
#pragma unroll
  for (int mi = 0; mi < 6; ++mi)
#pragma unroll
    for (int ni = 0; ni < 4; ++ni)
#pragma unroll
      for (int r = 0; r < 4; ++r) {
        size_t off = (size_t)(orow + mi * 16 + r) * HWN + ocol + ni * 16;
        if (OUTBF) ((unsigned short*)Y)[off] = f2bf(acc[mi][ni][r]);
        else       ((float*)Y)[off] = acc[mi][ni][r];
      }
}

// q0k0v0[b][j] = W_j @ x[b] (full M=384 per block). grid (128, 8, 3).
// XCD swizzle keeps the 3 j-blocks sharing one B-panel adjacent (L2 reuse).
__global__ __launch_bounds__(512) void k_conv_mfma(
    const unsigned short* __restrict__ Wc, const unsigned short* __restrict__ XT,
    unsigned short* __restrict__ Y)
{
  int g0 = (int)blockIdx.y * 128 + blockIdx.x;       // 0..1023 (b,nt)
  int lin = g0 * 3 + blockIdx.z;                     // 0..3071
  int swz = (lin & 7) * 384 + (lin >> 3);
  int g = swz / 3, j = swz - g * 3;
  int bb = g >> 7, nt = g & 127;
  gemm384_body<1>(Wc + j * WELEM, XT + (size_t)bb * PERT,
                  Y + (size_t)bb * 3 * PERT + (size_t)j * PERT, nt * 128);
}

// out[b] = M[b] @ v[b] (full M=384). grid (128, 8).
__global__ __launch_bounds__(512) void k_final_mfma(
    const unsigned short* __restrict__ M, const unsigned short* __restrict__ vT,
    float* __restrict__ out)
{
  int lin = (int)blockIdx.y * 128 + blockIdx.x;      // 0..1023
  int swz = (lin & 7) * 128 + (lin >> 3);
  int bb = swz >> 7, nt = swz & 127;
  gemm384_body<0>(M + (size_t)bb * WELEM, vT + (size_t)bb * PERT,
                  out + (size_t)bb * PERT, nt * 128);
}

// transpose+convert x[b][c][n] f32 -> XT[b][n][c] bf16, rows XOR-swizzled.
__global__ __launch_bounds__(256) void k_transpose_x(
    const float* __restrict__ x, unsigned short* __restrict__ XT)
{
  __shared__ unsigned short S[64][72];
  int n0 = blockIdx.x * 64, c0 = blockIdx.y * 64;
  const float* xb = x + (size_t)blockIdx.z * PERT;
  unsigned short* XTb = XT + (size_t)blockIdx.z * PERT;
  int t = threadIdx.x;
  int cl = t >> 2, ns = (t & 3) * 16;
  const float* src = &xb[(size_t)(c0 + cl) * HWN + n0 + ns];
#pragma unroll
  for (int i = 0; i < 16; i += 4) {
    float4 v = *reinterpret_cast<const float4*>(&src[i]);
    S[cl][ns + i + 0] = f2bf(v.x);
    S[cl][ns + i + 1] = f2bf(v.y);
    S[cl][ns + i + 2] = f2bf(v.z);
    S[cl][ns + i + 3] = f2bf(v.w);
  }
  __syncthreads();
  int nl = t >> 2, cs = (t & 3) * 16;
  unsigned short tmp[16];
#pragma unroll
  for (int i = 0; i < 16; ++i) tmp[i] = S[cs + i][nl];
  u16x8 p0, p1;
#pragma unroll
  for (int i = 0; i < 8; ++i) { p0[i] = tmp[i]; p1[i] = tmp[8 + i]; }
  char* rowb = (char*)XTb + (size_t)(n0 + nl) * (DIMC * 2);
  int cb = (c0 + cs) * 2;
  int sw = (nl & 7) << 4;
  *reinterpret_cast<u16x8*>(rowb + ((cb) ^ sw)) = p0;
  *reinterpret_cast<u16x8*>(rowb + ((cb + 16) ^ sw)) = p1;
}

// w -> bf16, stored XOR-swizzled per 64-elem k-chunk (A-operand layout).
__global__ __launch_bounds__(256) void k_convert_w(
    const float* __restrict__ w0, const float* __restrict__ w1,
    const float* __restrict__ w2, unsigned short* __restrict__ Wc)
{
  int idx = blockIdx.x * 256 + threadIdx.x;      // < 3*147456
  int j = idx / WELEM, r = idx - j * WELEM;
  int m = r / DIMC, k = r - m * DIMC;
  const float* s = (j == 0) ? w0 : (j == 1) ? w1 : w2;
  int kd = (k & ~63) | ((k & 63) ^ ((m & 7) << 3));
  Wc[j * WELEM + m * DIMC + kd] = f2bf(s[r]);
}

// depthwise 3x3 SAME for q,k planes only (j<2), bf16 in/out, 16 px/thread;
// halo via __shfl. 4 blocks per plane; per-block sum-of-squares partial.
__global__ __launch_bounds__(256) void k_dwconv(
    const unsigned short* __restrict__ Yin, const float* __restrict__ dw0,
    const float* __restrict__ dw1,
    unsigned short* __restrict__ Zout, float* __restrict__ partial)
{
  __shared__ float red[4];
  int gid = blockIdx.x * 256 + threadIdx.x;    // unit = 16 px
  int plane = gid >> 10;                        // 1024 units per plane
  int rem = gid & 1023;
  int b = plane / 768;
  int pl = plane - b * 768;                     // j*384 + c
  int j = pl / DIMC;
  int c = pl - j * DIMC;
  int h = rem >> 3;
  int wg = (rem & 7) << 4;                      // 0,16,...,112
  int lane = threadIdx.x & 63;                  // lane&7 == rem&7
  const float* dw = ((j == 0) ? dw0 : dw1) + c * 9;
  const unsigned short* src = Yin + ((size_t)(b * 3 + j) * DIMC + c) * HWN;

  float acc[16];
#pragma unroll
  for (int i = 0; i < 16; ++i) acc[i] = 0.f;

#pragma unroll
  for (int dy = -1; dy <= 1; ++dy) {
    int hh = h + dy;
    bool valid = (hh >= 0) && (hh < IMW);
    float mf[16];
    if (valid) {
      const unsigned short* row = src + hh * IMW + wg;
      u16x8 a0 = *reinterpret_cast<const u16x8*>(row);
      u16x8 a1 = *reinterpret_cast<const u16x8*>(row + 8);
#pragma unroll
      for (int i = 0; i < 8; ++i) { mf[i] = bf2f(a0[i]); mf[8 + i] = bf2f(a1[i]); }
    } else {
#pragma unroll
      for (int i = 0; i < 16; ++i) mf[i] = 0.f;
    }
    float lf = __shfl_up(mf[15], 1);
    float rf = __shfl_down(mf[0], 1);
    if ((lane & 7) == 0) lf = 0.f;
    if ((lane & 7) == 7) rf = 0.f;
    float t0 = dw[(dy + 1) * 3], t1 = dw[(dy + 1) * 3 + 1], t2 = dw[(dy + 1) * 3 + 2];
    acc[0] = fmaf(lf, t0, fmaf(mf[0], t1, fmaf(mf[1], t2, acc[0])));
#pragma unroll
    for (int i = 1; i < 15; ++i)
      acc[i] = fmaf(mf[i - 1], t0, fmaf(mf[i], t1, fmaf(mf[i + 1], t2, acc[i])));
    acc[15] = fmaf(mf[14], t0, fmaf(mf[15], t1, fmaf(rf, t2, acc[15])));
  }

  u16x8 o0, o1;
#pragma unroll
  for (int i = 0; i < 8; ++i) { o0[i] = f2bf(acc[i]); o1[i] = f2bf(acc[8 + i]); }
  unsigned short* dst =
      Zout + ((size_t)(b * 3 + j) * DIMC + c) * HWN + h * IMW + wg;
  *reinterpret_cast<u16x8*>(dst) = o0;
  *reinterpret_cast<u16x8*>(dst + 8) = o1;

  float s = 0.f;
#pragma unroll
  for (int i = 0; i < 16; ++i) s = fmaf(acc[i], acc[i], s);
#pragma unroll
  for (int off = 32; off > 0; off >>= 1) s += __shfl_down(s, off);
  if ((threadIdx.x & 63) == 0) red[threadIdx.x >> 6] = s;
  __syncthreads();
  if (threadIdx.x == 0)
    partial[blockIdx.x] = red[0] + red[1] + red[2] + red[3];
}

// depthwise 3x3 for v planes, FUSED with transpose: writes ONLY vT[b][n][c]
// bf16 (rows XOR-swizzled, B-operand layout). grid (128 h, 12 cgrp, 8 b).
__global__ __launch_bounds__(256) void k_dwconv_v(
    const unsigned short* __restrict__ Yin, const float* __restrict__ dw2,
    unsigned short* __restrict__ vT)
{
  __shared__ unsigned short S[128][40];   // [px][c_l]
  int h = blockIdx.x;
  int cgrp = blockIdx.y;
  int b = blockIdx.z;
  int t = threadIdx.x;
  int c_l = t >> 3;            // 0..31
  int seg = t & 7;
  int wg = seg << 4;
  int lane = t & 63;           // lane&7 == seg
  int c = cgrp * 32 + c_l;
  const float* dw = dw2 + c * 9;
  const unsigned short* src = Yin + ((size_t)(b * 3 + 2) * DIMC + c) * HWN;

  float acc[16];
#pragma unroll
  for (int i = 0; i < 16; ++i) acc[i] = 0.f;

#pragma unroll
  for (int dy = -1; dy <= 1; ++dy) {
    int hh = h + dy;
    bool valid = (hh >= 0) && (hh < IMW);
    float mf[16];
    if (valid) {
      const unsigned short* row = src + hh * IMW + wg;
      u16x8 a0 = *reinterpret_cast<const u16x8*>(row);
      u16x8 a1 = *reinterpret_cast<const u16x8*>(row + 8);
#pragma unroll
      for (int i = 0; i < 8; ++i) { mf[i] = bf2f(a0[i]); mf[8 + i] = bf2f(a1[i]); }
    } else {
#pragma unroll
      for (int i = 0; i < 16; ++i) mf[i] = 0.f;
    }
    float lf = __shfl_up(mf[15], 1);
    float rf = __shfl_down(mf[0], 1);
    if ((lane & 7) == 0) lf = 0.f;
    if ((lane & 7) == 7) rf = 0.f;
    float t0 = dw[(dy + 1) * 3], t1 = dw[(dy + 1) * 3 + 1], t2 = dw[(dy + 1) * 3 + 2];
    acc[0] = fmaf(lf, t0, fmaf(mf[0], t1, fmaf(mf[1], t2, acc[0])));
#pragma unroll
    for (int i = 1; i < 15; ++i)
      acc[i] = fmaf(mf[i - 1], t0, fmaf(mf[i], t1, fmaf(mf[i + 1], t2, acc[i])));
    acc[15] = fmaf(mf[14], t0, fmaf(mf[15], t1, fmaf(rf, t2, acc[15])));
  }

#pragma unroll
  for (int i = 0; i < 16; ++i) S[wg + i][c_l] = f2bf(acc[i]);
  __syncthreads();

  int px = t >> 1, half = t & 1;
  int n = h * IMW + px;
  u16x8 p0 = *reinterpret_cast<const u16x8*>(&S[px][half * 16]);
  u16x8 p1 = *reinterpret_cast<const u16x8*>(&S[px][half * 16 + 8]);
  char* rowb = (char*)(vT + (size_t)b * PERT) + (size_t)n * (DIMC * 2);
  int cb = (cgrp * 32 + half * 16) * 2;
  int sw = (n & 7) << 4;
  int chunk = cb & ~127, off = cb & 127;
  *reinterpret_cast<u16x8*>(rowb + chunk + ((off) ^ sw)) = p0;
  *reinterpret_cast<u16x8*>(rowb + chunk + ((off + 16) ^ sw)) = p1;
}

// q@k^T partials: grid 512 = (b, h, slice of 2048 px). 4 waves x 512 px.
__global__ __launch_bounds__(256) void k_qk_mfma(
    const unsigned short* __restrict__ qkv, float* __restrict__ Spart)
{
  __shared__ float Sred[4][2304];
  int blk = blockIdx.x;
  int b = blk >> 6, h = (blk >> 3) & 7, slice = blk & 7;
  int tid = threadIdx.x, lane = tid & 63, w = tid >> 6;
  const unsigned short* qb = qkv + ((size_t)b * 3 * DIMC + h * CHD) * HWN;
  const unsigned short* kb = qb + (size_t)DIMC * HWN;
  const int row = lane & 15;
  const int ko = (lane >> 4) << 3;
  const int n0 = slice * 2048 + w * 512;

  f32x4 acc[3][3];
#pragma unroll
  for (int i = 0; i < 3; ++i)
#pragma unroll
    for (int j = 0; j < 3; ++j) acc[i][j] = (f32x4){0.f, 0.f, 0.f, 0.f};

  for (int ns = n0; ns < n0 + 512; ns += 32) {
    short8 aq[3], bk[3];
#pragma unroll
    for (int mi = 0; mi < 3; ++mi)
      aq[mi] = *reinterpret_cast<const short8*>(&qb[(size_t)(mi * 16 + row) * HWN + ns + ko]);
#pragma unroll
    for (int ni = 0; ni < 3; ++ni)
      bk[ni] = *reinterpret_cast<const short8*>(&kb[(size_t)(ni * 16 + row) * HWN + ns + ko]);
#pragma unroll
    for (int mi = 0; mi < 3; ++mi)
#pragma unroll
      for (int ni = 0; ni < 3; ++ni)
        acc[mi][ni] = __builtin_amdgcn_mfma_f32_16x16x32_bf16(
            aq[mi], bk[ni], acc[mi][ni], 0, 0, 0);
  }
  const int c0 = (lane >> 4) << 2;
#pragma unroll
  for (int mi = 0; mi < 3; ++mi)
#pragma unroll
    for (int ni = 0; ni < 3; ++ni)
#pragma unroll
      for (int r = 0; r < 4; ++r)
        Sred[w][(mi * 16 + c0 + r) * 48 + ni * 16 + row] = acc[mi][ni][r];
  __syncthreads();
  float* dst = Spart + (size_t)blk * 2304;
#pragma unroll
  for (int i = 0; i < 9; ++i) {
    int e = tid + i * 256;
    dst[e] = Sred[0][e] + Sred[1][e] + Sred[2][e] + Sred[3][e];
  }
}

// slice-sum + L2-norm scale + softmax. grid = 8 (per b), 384 thr = row (h,c).
__global__ __launch_bounds__(384) void k_attn_sm(
    const float* __restrict__ Spart, const float* __restrict__ partial,
    const float* __restrict__ temp, float* __restrict__ Aat)
{
  __shared__ float sk[DIMC];
  int b = blockIdx.x, t = threadIdx.x;
  int h = t / CHD, c = t - h * CHD;
  float sq = 0.f, skk = 0.f;
#pragma unroll
  for (int s = 0; s < 4; ++s) {
    sq  += partial[((size_t)b * 768 + t) * 4 + s];
    skk += partial[((size_t)b * 768 + DIMC + t) * 4 + s];
  }
  sk[t] = 1.f / fmaxf(sqrtf(skk), 1e-12f);
  float invq = 1.f / fmaxf(sqrtf(sq), 1e-12f);
  __syncthreads();
  float vals[CHD];
#pragma unroll
  for (int d = 0; d < CHD; ++d) vals[d] = 0.f;
  for (int sl = 0; sl < 8; ++sl) {
    const float* sp = Spart + (size_t)(b * 64 + h * 8 + sl) * 2304 + c * 48;
#pragma unroll
    for (int d = 0; d < CHD; ++d) vals[d] += sp[d];
  }
  float tp = temp[h];
  float vq = invq * tp;
  float mx = -1e30f;
#pragma unroll
  for (int d = 0; d < CHD; ++d) {
    vals[d] *= vq * sk[h * CHD + d];
    mx = fmaxf(mx, vals[d]);
  }
  float sum = 0.f;
#pragma unroll
  for (int d = 0; d < CHD; ++d) { vals[d] = expf(vals[d] - mx); sum += vals[d]; }
  float inv = 1.f / sum;
  float* Arow = Aat + ((size_t)(b * 8 + h) * 48 + c) * 48;
#pragma unroll
  for (int d = 0; d < CHD; ++d) Arow[d] = vals[d] * inv;
}

// M[b][o][h*48+d] = sum_c wproj[o][h*48+c] * A[b][h*48+c][d], bf16 out,
// stored XOR-swizzled (A-operand layout for k_final_mfma).
__global__ __launch_bounds__(256) void k_combine(
    const float* __restrict__ wproj, const float* __restrict__ Aat,
    unsigned short* __restrict__ M)
{
  int idx = blockIdx.x * 256 + threadIdx.x;      // over 8*384*384
  int b = idx / WELEM;
  int r2 = idx - b * WELEM;
  int o = r2 / DIMC;
  int dg = r2 - o * DIMC;
  int h = dg / CHD, d = dg - h * CHD;
  const float* wrow = wproj + (size_t)o * DIMC + h * CHD;
  const float* Acol = Aat + (size_t)b * DIMC * CHD + (size_t)(h * CHD) * CHD + d;
  float s = 0.f;
#pragma unroll
  for (int c = 0; c < CHD; ++c)
    s = fmaf(wrow[c], Acol[c * CHD], s);
  int dd = (dg & ~63) | ((dg & 63) ^ ((o & 7) << 3));
  M[b * WELEM + o * DIMC + dd] = f2bf(s);
}

extern "C" void kernel_launch(void* const* d_in, const int* in_sizes, int n_in,
                              void* d_out, int out_size, void* d_ws, size_t ws_size,
                              hipStream_t stream)
{
  const float* x     = (const float*)d_in[0];
  const float* w0    = (const float*)d_in[1];
  const float* w1    = (const float*)d_in[2];
  const float* w2    = (const float*)d_in[3];
  const float* dw0   = (const float*)d_in[4];
  const float* dw1   = (const float*)d_in[5];
  const float* dw2   = (const float*)d_in[6];
  const float* wproj = (const float*)d_in[7];
  const float* temp  = (const float*)d_in[8];
  float* out = (float*)d_out;

  // ws layout. vT aliases XT (XT dead after conv_mfma; dwconv_v runs after).
  char* p = (char*)d_ws;
  unsigned short* Wc     = (unsigned short*)p;  p += (size_t)3 * WELEM * 2;            // 884,736
  unsigned short* XT     = (unsigned short*)p;  p += (size_t)NB * PERT * 2;            // 100.7 MB
  unsigned short* q0k0v0 = (unsigned short*)p;  p += (size_t)NB * 3 * PERT * 2;        // 302 MB
  unsigned short* qkv    = (unsigned short*)p;  p += (size_t)NB * 3 * PERT * 2;        // 302 MB (v third unused)
  float* Spart   = (float*)p;  p += (size_t)512 * 2304 * 4;                            // 4.7 MB
  float* Aat     = (float*)p;  p += (size_t)NB * DIMC * CHD * 4;                       // 590 KB
  float* partial = (float*)p;  p += (size_t)NB * 2 * DIMC * 4 * 4;                     // 98 KB
  unsigned short* Mbf = (unsigned short*)p;                                            // 2.36 MB
  unsigned short* vT = XT;   // alias

  k_convert_w<<<(3 * WELEM + 255) / 256, 256, 0, stream>>>(w0, w1, w2, Wc);
  k_transpose_x<<<dim3(256, 6, NB), 256, 0, stream>>>(x, XT);
  k_conv_mfma<<<dim3(128, NB, 3), 512, 0, stream>>>(Wc, XT, q0k0v0);
  k_dwconv<<<NB * 2 * DIMC * 4, 256, 0, stream>>>(q0k0v0, dw0, dw1, qkv, partial);
  k_dwconv_v<<<dim3(128, 12, NB), 256, 0, stream>>>(q0k0v0, dw2, vT);
  k_qk_mfma<<<512, 256, 0, stream>>>(qkv, Spart);
  k_attn_sm<<<NB, 384, 0, stream>>>(Spart, partial, temp, Aat);
  k_combine<<<(NB * WELEM) / 256, 256, 0, stream>>>(wproj, Aat, Mbf);
  k_final_mfma<<<dim3(128, NB), 512, 0, stream>>>(Mbf, vT, out);
  (void)in_sizes; (void)n_in; (void)out_size; (void)ws_size;
}